// Round 5
// baseline (1793.772 us; speedup 1.0000x reference)
//
#include <hip/hip_runtime.h>
#include <hip/hip_bf16.h>

#define NS 512     // states
#define MS 256     // symbols
#define TB 256     // sequence length
#define NGRP 16    // batch groups
#define NSL 4      // state slices (peer WGs) per group
#define SLST 128   // states per slice
#define BPG 16     // batches per group

// workspace byte offsets
#define OFF_LOGET  0u
#define OFF_LOGPRI 524288u
#define OFF_TEXP   526336u
#define OFF_AEX    1050624u   // bf16 [16 grp][2 par][16 b][512 k] = 512KB, tagged u64 chunks

typedef __attribute__((ext_vector_type(8))) short short8;
typedef __attribute__((ext_vector_type(4))) float f32x4;

__device__ __forceinline__ unsigned long long ld_u64_agent(const unsigned long long* p) {
    return __hip_atomic_load(p, __ATOMIC_RELAXED, __HIP_MEMORY_SCOPE_AGENT);
}
__device__ __forceinline__ void st_u64_agent(unsigned long long* p, unsigned long long v) {
    __hip_atomic_store(p, v, __ATOMIC_RELAXED, __HIP_MEMORY_SCOPE_AGENT);
}
__device__ __forceinline__ float u2f(unsigned u) { float f; __builtin_memcpy(&f, &u, 4); return f; }
__device__ __forceinline__ unsigned short bf_bits(float f) {
    __hip_bfloat16 h = __float2bfloat16(f);
    unsigned short u; __builtin_memcpy(&u, &h, 2); return u;
}

__global__ void k_emission(const float* __restrict__ E, float* __restrict__ logET) {
    int n = blockIdx.x;
    int lane = threadIdx.x;
    const float* row = E + (size_t)n * MS;
    float v[4]; float mx = -1e30f;
#pragma unroll
    for (int j = 0; j < 4; ++j) { v[j] = row[lane + 64 * j]; mx = fmaxf(mx, v[j]); }
#pragma unroll
    for (int off = 1; off < 64; off <<= 1) mx = fmaxf(mx, __shfl_xor(mx, off));
    float s = 0.f;
#pragma unroll
    for (int j = 0; j < 4; ++j) s += __expf(v[j] - mx);
#pragma unroll
    for (int off = 1; off < 64; off <<= 1) s += __shfl_xor(s, off);
    float lse = mx + __logf(s);
#pragma unroll
    for (int j = 0; j < 4; ++j) logET[(size_t)(lane + 64 * j) * NS + n] = v[j] - lse;
}

__global__ void k_transition(const float* __restrict__ U, __hip_bfloat16* __restrict__ Texp) {
    int k = blockIdx.x;
    int lane = threadIdx.x;
    float v[8]; float mx = -1e30f;
#pragma unroll
    for (int j = 0; j < 8; ++j) { v[j] = U[(size_t)(lane + 64 * j) * NS + k]; mx = fmaxf(mx, v[j]); }
#pragma unroll
    for (int off = 1; off < 64; off <<= 1) mx = fmaxf(mx, __shfl_xor(mx, off));
    float s = 0.f;
#pragma unroll
    for (int j = 0; j < 8; ++j) s += __expf(v[j] - mx);
#pragma unroll
    for (int off = 1; off < 64; off <<= 1) s += __shfl_xor(s, off);
    float lse = mx + __logf(s);
#pragma unroll
    for (int j = 0; j < 8; ++j)
        Texp[(size_t)(lane + 64 * j) * NS + k] = __float2bfloat16(__expf(v[j] - lse));
}

__global__ void k_priors(const float* __restrict__ U, float* __restrict__ lp) {
    int lane = threadIdx.x;
    float v[8]; float mx = -1e30f;
#pragma unroll
    for (int j = 0; j < 8; ++j) { v[j] = U[lane + 64 * j]; mx = fmaxf(mx, v[j]); }
#pragma unroll
    for (int off = 1; off < 64; off <<= 1) mx = fmaxf(mx, __shfl_xor(mx, off));
    float s = 0.f;
#pragma unroll
    for (int j = 0; j < 8; ++j) s += __expf(v[j] - mx);
#pragma unroll
    for (int off = 1; off < 64; off <<= 1) s += __shfl_xor(s, off);
    float lse = mx + __logf(s);
#pragma unroll
    for (int j = 0; j < 8; ++j) lp[lane + 64 * j] = v[j] - lse;
}

// 64 WGs: group g owns batches [g*16,(g+1)*16); slice j owns states [j*128,(j+1)*128)
// with T-rows LDS-resident (XOR-swizzled). Cross-WG exchange = self-validating
// tagged u64 messages in MALL (bit63 = step phase). No flags, no fences, no
// barriers in the main loop; waves fully decoupled. Normalizer & row-sums are
// recomputed per-consumer from the bf16 A data (bit-identical everywhere).
__launch_bounds__(256, 1)
__global__ void k_forward(const int* __restrict__ batch, const float* __restrict__ logET,
                          const __hip_bfloat16* __restrict__ Texp,
                          const float* __restrict__ logpri,
                          unsigned long long* __restrict__ Aex64,
                          float* __restrict__ out) {
    __shared__ __align__(16) char Tsl[SLST * 1024];            // 128KB swizzled T slice
    __shared__ int syms[BPG * TB];                             // 16KB
    __shared__ __align__(16) unsigned short rep[4][BPG][32];   // 4KB per-wave repack

    const int tid = threadIdx.x;
    const int lane = tid & 63;
    const int wv = tid >> 6;      // wave -> k/state sub-range [wv*32, wv*32+32)
    const int hi = lane >> 4;     // 0..3
    const int lo = lane & 15;
    const int g  = blockIdx.x >> 2;
    const int j  = blockIdx.x & 3;
    const int b0 = g * BPG;
    const int i0 = j * SLST;

    // ---- stage T slice into LDS with XOR swizzle: byte ^= ((row&7)<<4) ----
    for (int c = tid; c < SLST * 64; c += 256) {
        int i = c >> 6, kc = c & 63;
        short8 vld = *reinterpret_cast<const short8*>(Texp + (size_t)(i0 + i) * NS + kc * 8);
        int off = ((i << 10) + (kc << 4)) ^ ((i & 7) << 4);
        *reinterpret_cast<short8*>(Tsl + off) = vld;
    }
    for (int idx = tid; idx < BPG * TB; idx += 256)
        syms[idx] = batch[b0 * TB + idx];
    __syncthreads();   // Tsl/syms ready; ONLY barrier in the kernel

    union U16B { unsigned long long q[2]; short8 s; };
    const unsigned long long TAGBIT = 1ull << 63;

    float nrmL = 0.f;     // normalizer for batch b = lo (bit-identical across waves)

    // ---- prologue t = 0: publish A(0) = exp(em0 + priors), par 0, phase 0 ----
    {
#pragma unroll
        for (int r = 0; r < 4; ++r) {
            int sym = syms[(hi * 4 + r) * TB];
#pragma unroll
            for (int nt = 0; nt < 2; ++nt) {
                int i = i0 + wv * 32 + nt * 16 + lo;
                float a = __expf(logET[(size_t)sym * NS + i] + logpri[i]);
                rep[wv][hi * 4 + r][nt * 16 + lo] = bf_bits(a);
            }
        }
        unsigned long long w0 = *reinterpret_cast<const unsigned long long*>(&rep[wv][lo][hi * 4]);
        unsigned long long w1 = *reinterpret_cast<const unsigned long long*>(&rep[wv][lo][16 + hi * 4]);
        unsigned long long* dst = Aex64 + ((size_t)(g * 2 + 0) * BPG + lo) * 128 + j * 32 + wv * 8 + hi;
        st_u64_agent(dst, w0);          // phase 0 -> tag bit stays 0
        st_u64_agent(dst + 4, w1);
    }

    // ---- main scan: iteration t consumes A(t-1), produces A(t) ----
    for (int t = 1; t < TB; ++t) {
        const int parR = (t - 1) & 1;
        const unsigned long long phR = (unsigned long long)(((t - 1) >> 1) & 1);
        const int parW = t & 1;
        const unsigned long long tagW = ((unsigned long long)((t >> 1) & 1)) << 63;

        // emission prefetch (constant, L2-warm) — independent of peers
        float em[4][2];
#pragma unroll
        for (int r = 0; r < 4; ++r) {
            int sym = syms[(hi * 4 + r) * TB + t];
#pragma unroll
            for (int nt = 0; nt < 2; ++nt)
                em[r][nt] = logET[(size_t)sym * NS + i0 + wv * 32 + nt * 16 + lo];
        }

        // ---- poll-load A(t-1) row b=lo: 32 tagged u64 chunks ----
        U16B af[16];
        const unsigned long long* abase =
            Aex64 + ((size_t)(g * 2 + parR) * BPG + lo) * 128 + hi * 2;
        unsigned pend = 0xFFFFFFFFu;
        while (pend) {
#pragma unroll
            for (int i = 0; i < 32; ++i)
                if (pend & (1u << i))
                    af[i >> 1].q[i & 1] = ld_u64_agent(abase + (i >> 1) * 8 + (i & 1));
#pragma unroll
            for (int i = 0; i < 32; ++i)
                if ((pend & (1u << i)) && (af[i >> 1].q[i & 1] >> 63) == phR)
                    pend &= ~(1u << i);
            if (pend) __builtin_amdgcn_s_sleep(1);
        }
#pragma unroll
        for (int i = 0; i < 32; ++i)
            af[i >> 1].q[i & 1] &= ~TAGBIT;

        // ---- GEMM: acc[nt] = sum_k A[b,k] * T[i,k] (K = 512) ----
        f32x4 acc[2] = {};
#pragma unroll
        for (int kb16 = 0; kb16 < 16; ++kb16) {
#pragma unroll
            for (int nt = 0; nt < 2; ++nt) {
                int il = wv * 32 + nt * 16 + lo;
                int off = ((il << 10) + ((kb16 * 32 + hi * 8) << 1)) ^ ((il & 7) << 4);
                short8 bfr = *reinterpret_cast<const short8*>(Tsl + off);
                acc[nt] = __builtin_amdgcn_mfma_f32_16x16x32_bf16(af[kb16].s, bfr, acc[nt], 0, 0, 0);
            }
        }

        // ---- row-sums q(t-1) from the loaded bf16 data (identical in all WGs) ----
        float qsl[4];
#pragma unroll
        for (int jj = 0; jj < 4; ++jj) {
            float s = 0.f;
#pragma unroll
            for (int c2 = 0; c2 < 8; ++c2) {
                unsigned long long x = af[jj * 4 + (c2 >> 1)].q[c2 & 1];
                unsigned xl = (unsigned)x, xh = (unsigned)(x >> 32);
                s += u2f(xl << 16); s += u2f(xl & 0xFFFF0000u);
                s += u2f(xh << 16); s += u2f(xh & 0xFFFF0000u);
            }
            s += __shfl_xor(s, 16);
            s += __shfl_xor(s, 32);
            qsl[jj] = s;   // slice-jj sum for batch lo
        }
        float qs = qsl[0] + qsl[1] + qsl[2] + qsl[3];
        float qm = fmaxf(fmaxf(qsl[0], qsl[1]), fmaxf(qsl[2], qsl[3]));
        float lqm = __logf(qm);

        if (j == 0 && wv == 0 && hi == 0)
            out[(size_t)(b0 + lo) * TB + (t - 1)] = nrmL + __logf(qs);
        nrmL += lqm;

        // per-r normalizer delta: dn[r] = log qm for batch hi*4+r
        float dn[4];
#pragma unroll
        for (int r = 0; r < 4; ++r) dn[r] = __shfl(lqm, hi * 4 + r);

        // ---- epilogue: a(t) = acc * exp(em - dlog qm); repack; tagged publish ----
#pragma unroll
        for (int r = 0; r < 4; ++r)
#pragma unroll
            for (int nt = 0; nt < 2; ++nt) {
                float a = acc[nt][r] * __expf(em[r][nt] - dn[r]);
                rep[wv][hi * 4 + r][nt * 16 + lo] = bf_bits(a);
            }
        unsigned long long w0 = *reinterpret_cast<const unsigned long long*>(&rep[wv][lo][hi * 4]);
        unsigned long long w1 = *reinterpret_cast<const unsigned long long*>(&rep[wv][lo][16 + hi * 4]);
        unsigned long long* dst = Aex64 + ((size_t)(g * 2 + parW) * BPG + lo) * 128 + j * 32 + wv * 8 + hi;
        st_u64_agent(dst, w0 | tagW);
        st_u64_agent(dst + 4, w1 | tagW);
    }

    // ---- final column t = 255 from A(255) (par 1, phase 1) ----
    if (j == 0 && wv == 0) {
        U16B af[16];
        const unsigned long long* abase =
            Aex64 + ((size_t)(g * 2 + 1) * BPG + lo) * 128 + hi * 2;
        unsigned pend = 0xFFFFFFFFu;
        while (pend) {
#pragma unroll
            for (int i = 0; i < 32; ++i)
                if (pend & (1u << i))
                    af[i >> 1].q[i & 1] = ld_u64_agent(abase + (i >> 1) * 8 + (i & 1));
#pragma unroll
            for (int i = 0; i < 32; ++i)
                if ((pend & (1u << i)) && (af[i >> 1].q[i & 1] >> 63) == 1ull)
                    pend &= ~(1u << i);
            if (pend) __builtin_amdgcn_s_sleep(1);
        }
        float qs = 0.f;
#pragma unroll
        for (int i = 0; i < 32; ++i) {
            unsigned long long x = af[i >> 1].q[i & 1] & ~TAGBIT;
            unsigned xl = (unsigned)x, xh = (unsigned)(x >> 32);
            qs += u2f(xl << 16); qs += u2f(xl & 0xFFFF0000u);
            qs += u2f(xh << 16); qs += u2f(xh & 0xFFFF0000u);
        }
        qs += __shfl_xor(qs, 16);
        qs += __shfl_xor(qs, 32);
        if (hi == 0)
            out[(size_t)(b0 + lo) * TB + 255] = nrmL + __logf(qs);
    }
}

extern "C" void kernel_launch(void* const* d_in, const int* in_sizes, int n_in,
                              void* d_out, int out_size, void* d_ws, size_t ws_size,
                              hipStream_t stream) {
    const int* batch = (const int*)d_in[0];
    const float* unE = (const float*)d_in[1];
    const float* unT = (const float*)d_in[2];
    const float* unP = (const float*)d_in[3];
    float* outp = (float*)d_out;

    char* ws = (char*)d_ws;
    float* logET = (float*)(ws + OFF_LOGET);
    float* logpri = (float*)(ws + OFF_LOGPRI);
    __hip_bfloat16* Texp = (__hip_bfloat16*)(ws + OFF_TEXP);
    unsigned long long* Aex64 = (unsigned long long*)(ws + OFF_AEX);

    // poison A-exchange (0xAA per byte -> tag bit 1 everywhere; blocks phase-0 reads)
    hipMemsetAsync(Aex64, 0xAA, (size_t)NGRP * 2 * BPG * NS * 2, stream);
    k_emission<<<NS, 64, 0, stream>>>(unE, logET);
    k_transition<<<NS, 64, 0, stream>>>(unT, Texp);
    k_priors<<<1, 64, 0, stream>>>(unP, logpri);
    k_forward<<<NGRP * NSL, 256, 0, stream>>>(batch, logET, Texp, logpri, Aex64, outp);
}